// Round 14
// baseline (17.418 us; speedup 1.0000x reference)
//
#include <hip/hip_runtime.h>

// Problem constants (from reference setup_inputs)
#define B_  4
#define H_  64
#define W_  64
#define C_  16
#define F_  32

typedef _Float16 h2 __attribute__((ext_vector_type(2)));

__device__ __forceinline__ h2 pack2(float a, float b) {
    h2 r; r.x = (_Float16)a; r.y = (_Float16)b; return r;
}
__device__ __forceinline__ float h2f(h2 v) { return __builtin_bit_cast(float, v); }
__device__ __forceinline__ h2 f2h(float v) { return __builtin_bit_cast(h2, v); }

// acc += m.x + m.y (f32 accumulate of a packed f16 pair)
__device__ __forceinline__ float acc_dot2(h2 m, float c) {
#if __has_builtin(__builtin_amdgcn_fdot2)
    h2 one; one.x = (_Float16)1.0f; one.y = (_Float16)1.0f;
    return __builtin_amdgcn_fdot2(m, one, c, false);
#else
    return c + (float)m.x + (float)m.y;
#endif
}

// Round-14 = round-13 (packed-f16 all-LDS champion) with all LDS reads
// widened to b128:
//  - weights [cc][qp(5)][f] float4 = (wt(2qp),wk(2qp),wt(2qp+1),wk(2qp+1)) -> 5 reads/cc
//  - x dual shifted copies xa (col) / xb (col-1), [row][cc][colq] float4 ->
//    ps=0 reads xa, ps=1 reads xb, both 16B-aligned -> 9 reads/cc (3/row)
// DS instr per cc per wave: 36 -> 14. Batch now fits in wide regs -> cc-loop
// unroll 2 for cross-iteration load/compute overlap (est ~100 VGPR live; no
// launch_bounds floor per r4/r8/r11 lesson).
__global__ __launch_bounds__(256) void mtp_main(const float* __restrict__ x,
                                                const float* __restrict__ kern,
                                                const float* __restrict__ tker,
                                                float* __restrict__ out) {
    __shared__ float4 wlds[8][5][32];   // 20480 B
    __shared__ float4 xa[3][8][9];      //  3456 B (h2 cols 0..35, col = padded col)
    __shared__ float4 xb[3][8][9];      //  3456 B (col = padded col - 1)

    const int tid  = threadIdx.x;
    const int bidx = blockIdx.x;        // (b*64 + i)*2 + half
    const int half = bidx & 1;
    const int i    = (bidx >> 1) & 63;
    const int b    = bidx >> 7;

    // ---- stage weights: 1280 slots = 5 * 256 ----
    #pragma unroll
    for (int e0 = 0; e0 < 5; ++e0) {
        int e  = e0 * 256 + tid;
        int f  = e & 31;
        int t  = e >> 5;
        int qp = t % 5;
        int cc = t / 5;
        int c0 = cc * 2, c1 = c0 + 1;
        int q0 = qp * 2;
        int q1 = (qp < 4) ? q0 + 1 : 8;          // dummy-valid for qp==4
        float4 v;
        v.x = h2f(pack2(tker[(q0 * C_ + c0) * F_ + f], tker[(q0 * C_ + c1) * F_ + f]));
        v.y = h2f(pack2(kern[(q0 * C_ + c0) * F_ + f], kern[(q0 * C_ + c1) * F_ + f]));
        h2 zt = (qp < 4) ? pack2(tker[(q1 * C_ + c0) * F_ + f], tker[(q1 * C_ + c1) * F_ + f])
                         : pack2(0.f, 0.f);
        h2 zk = (qp < 4) ? pack2(kern[(q1 * C_ + c0) * F_ + f], kern[(q1 * C_ + c1) * F_ + f])
                         : pack2(0.f, 0.f);
        v.z = h2f(zt);
        v.w = h2f(zk);
        wlds[cc][qp][f] = v;
    }
    // ---- stage x halo (zero-padded) into both shifted copies ----
    float* xaf = reinterpret_cast<float*>(xa);   // [row][cc][col_h2(36)]
    float* xbf = reinterpret_cast<float*>(xb);
    for (int e = tid; e < 3 * 34 * 4; e += 256) {
        int cc4 = e & 3;
        int t   = e >> 2;
        int cl  = t % 34;                        // local padded col
        int di  = t / 34;
        int ro  = i + di - 1;
        int co  = half * 32 + cl - 1;
        float4 v = make_float4(0.f, 0.f, 0.f, 0.f);
        if (ro >= 0 && ro < H_ && co >= 0 && co < W_)
            v = *reinterpret_cast<const float4*>(
                    x + ((b * H_ + ro) * W_ + co) * C_ + cc4 * 4);
        float p0 = h2f(pack2(v.x, v.y));
        float p1 = h2f(pack2(v.z, v.w));
        int cc0 = cc4 * 2, cc1 = cc0 + 1;
        xaf[(di * 8 + cc0) * 36 + cl] = p0;
        xaf[(di * 8 + cc1) * 36 + cl] = p1;
        if (cl >= 1) {
            xbf[(di * 8 + cc0) * 36 + cl - 1] = p0;
            xbf[(di * 8 + cc1) * 36 + cl - 1] = p1;
        }
    }
    __syncthreads();

    const int lane = tid & 63;
    const int f    = lane & 31;
    const int ps   = lane >> 5;
    const int w    = tid >> 6;          // wave 0..3
    const int w2   = w * 2;             // window base in float4 units (= col w*8)

    float acc[4][4];                    // [it][r]
    #pragma unroll
    for (int it = 0; it < 4; ++it)
        #pragma unroll
        for (int r = 0; r < 4; ++r) acc[it][r] = 0.f;

    // per-lane x window base pointer (ps selects the shifted copy)
    const float4* xp0 = (ps ? &xb[0][0][0] : &xa[0][0][0]) + w2;

    #pragma unroll 2
    for (int cc = 0; cc < 8; ++cc) {
        // weights: 5 ds_read_b128
        float4 ws0 = wlds[cc][0][f];
        float4 ws1 = wlds[cc][1][f];
        float4 ws2 = wlds[cc][2][f];
        float4 ws3 = wlds[cc][3][f];
        float4 ws4 = wlds[cc][4][f];
        h2 wt[9], wk[9];
        wt[0] = f2h(ws0.x); wk[0] = f2h(ws0.y); wt[1] = f2h(ws0.z); wk[1] = f2h(ws0.w);
        wt[2] = f2h(ws1.x); wk[2] = f2h(ws1.y); wt[3] = f2h(ws1.z); wk[3] = f2h(ws1.w);
        wt[4] = f2h(ws2.x); wk[4] = f2h(ws2.y); wt[5] = f2h(ws2.z); wk[5] = f2h(ws2.w);
        wt[6] = f2h(ws3.x); wk[6] = f2h(ws3.y); wt[7] = f2h(ws3.z); wk[7] = f2h(ws3.w);
        wt[8] = f2h(ws4.x); wk[8] = f2h(ws4.y);

        // x window: 3 rows x 3 aligned float4 (12 h2 cols, 9 used)
        const float4* xp = xp0 + cc * 9;
        float xc[3][12];
        #pragma unroll
        for (int dr = 0; dr < 3; ++dr) {
            float4 a = xp[dr * 72 + 0];
            float4 bq4 = xp[dr * 72 + 1];
            float4 c = xp[dr * 72 + 2];
            xc[dr][0] = a.x;  xc[dr][1] = a.y;  xc[dr][2]  = a.z;  xc[dr][3]  = a.w;
            xc[dr][4] = bq4.x; xc[dr][5] = bq4.y; xc[dr][6] = bq4.z; xc[dr][7] = bq4.w;
            xc[dr][8] = c.x;  xc[dr][9] = c.y;  xc[dr][10] = c.z;  xc[dr][11] = c.w;
        }

        #pragma unroll
        for (int it = 0; it < 4; ++it) {
            #pragma unroll
            for (int r = 0; r < 4; ++r) {
                h2 z[9];
                #pragma unroll
                for (int q = 0; q < 9; ++q) {
                    const int a = q / 3, bq = q % 3;
                    int di, dj;
                    switch (r) {   // x position = rot_r^{-1}(weight position q)
                        case 0:  di = a;      dj = bq;     break;
                        case 1:  di = 2 - bq; dj = a;      break;
                        case 2:  di = 2 - a;  dj = 2 - bq; break;
                        default: di = bq;     dj = 2 - a;  break;
                    }
                    z[q] = f2h(xc[di][it * 2 + dj]) * wt[q] + wk[q];   // v_pk_fma_f16
                }
                h2 m1 = __builtin_elementwise_max(__builtin_elementwise_max(z[0], z[1]), z[2]);
                h2 m2 = __builtin_elementwise_max(__builtin_elementwise_max(z[3], z[4]), z[5]);
                h2 m3 = __builtin_elementwise_max(__builtin_elementwise_max(z[6], z[7]), z[8]);
                h2 mm = __builtin_elementwise_max(__builtin_elementwise_max(m1, m2), m3);
                acc[it][r] = acc_dot2(mm, acc[it][r]);   // f32 accumulate
            }
        }
    }

    // ---- store: out[b, r, i, jg + it*2, f]; per (r,it) wave stores 256B
    const int jg = half * 32 + w * 8 + ps;
    #pragma unroll
    for (int r = 0; r < 4; ++r) {
        float* op = out + ((((b * 4 + r) * H_ + i) * W_ + jg) * F_ + f);
        #pragma unroll
        for (int it = 0; it < 4; ++it)
            op[it * 2 * F_] = acc[it][r];
    }
}

extern "C" void kernel_launch(void* const* d_in, const int* in_sizes, int n_in,
                              void* d_out, int out_size, void* d_ws, size_t ws_size,
                              hipStream_t stream) {
    const float* x    = (const float*)d_in[0];
    const float* kern = (const float*)d_in[1];
    const float* tker = (const float*)d_in[2];
    float* out = (float*)d_out;

    hipLaunchKernelGGL(mtp_main, dim3(B_ * H_ * 2), dim3(256), 0, stream,
                       x, kern, tker, out);
}

// Round 15
// 17.223 us; speedup vs baseline: 1.0113x; 1.0113x over previous
//
#include <hip/hip_runtime.h>

// Problem constants (from reference setup_inputs)
#define B_  4
#define H_  64
#define W_  64
#define C_  16
#define F_  32

typedef _Float16 h2 __attribute__((ext_vector_type(2)));

__device__ __forceinline__ h2 pack2(float a, float b) {
    h2 r; r.x = (_Float16)a; r.y = (_Float16)b; return r;
}
__device__ __forceinline__ float h2f(h2 v) { return __builtin_bit_cast(float, v); }
__device__ __forceinline__ h2 f2h(float v) { return __builtin_bit_cast(h2, v); }

// acc += m.x + m.y (f32 accumulate of a packed f16 pair)
__device__ __forceinline__ float acc_dot2(h2 m, float c) {
#if __has_builtin(__builtin_amdgcn_fdot2)
    h2 one; one.x = (_Float16)1.0f; one.y = (_Float16)1.0f;
    return __builtin_amdgcn_fdot2(m, one, c, false);
#else
    return c + (float)m.x + (float)m.y;
#endif
}

// Round-15 = round-14 wide-b128-LDS layout with round-13's cc-loop unroll 1.
// Deconfounds r14 (which changed layout AND unroll together and regressed):
//  - vs r14: only `#pragma unroll 2` -> `#pragma unroll 1` (cuts live regs ~2x)
//  - vs r13: only the LDS layout (DS instr/cc: 36 -> 14 via b128 reads)
// DS/CU model: 14x8x8waves x ~7cyc ~= 6.3k cyc < VALU 9.2k cyc/SIMD -> main
// should become VALU-limited (~8-9 us incl staging/stores).
__global__ __launch_bounds__(256) void mtp_main(const float* __restrict__ x,
                                                const float* __restrict__ kern,
                                                const float* __restrict__ tker,
                                                float* __restrict__ out) {
    __shared__ float4 wlds[8][5][32];   // 20480 B: (wt2q,wk2q,wt2q+1,wk2q+1)
    __shared__ float4 xa[3][8][9];      //  3456 B (h2 cols, col = padded col)
    __shared__ float4 xb[3][8][9];      //  3456 B (col = padded col - 1)

    const int tid  = threadIdx.x;
    const int bidx = blockIdx.x;        // (b*64 + i)*2 + half
    const int half = bidx & 1;
    const int i    = (bidx >> 1) & 63;
    const int b    = bidx >> 7;

    // ---- stage weights: 1280 slots = 5 * 256 ----
    #pragma unroll
    for (int e0 = 0; e0 < 5; ++e0) {
        int e  = e0 * 256 + tid;
        int f  = e & 31;
        int t  = e >> 5;
        int qp = t % 5;
        int cc = t / 5;
        int c0 = cc * 2, c1 = c0 + 1;
        int q0 = qp * 2;
        int q1 = (qp < 4) ? q0 + 1 : 8;          // dummy-valid for qp==4
        float4 v;
        v.x = h2f(pack2(tker[(q0 * C_ + c0) * F_ + f], tker[(q0 * C_ + c1) * F_ + f]));
        v.y = h2f(pack2(kern[(q0 * C_ + c0) * F_ + f], kern[(q0 * C_ + c1) * F_ + f]));
        h2 zt = (qp < 4) ? pack2(tker[(q1 * C_ + c0) * F_ + f], tker[(q1 * C_ + c1) * F_ + f])
                         : pack2(0.f, 0.f);
        h2 zk = (qp < 4) ? pack2(kern[(q1 * C_ + c0) * F_ + f], kern[(q1 * C_ + c1) * F_ + f])
                         : pack2(0.f, 0.f);
        v.z = h2f(zt);
        v.w = h2f(zk);
        wlds[cc][qp][f] = v;
    }
    // ---- stage x halo (zero-padded) into both shifted copies ----
    float* xaf = reinterpret_cast<float*>(xa);   // [row][cc][col_h2(36)]
    float* xbf = reinterpret_cast<float*>(xb);
    for (int e = tid; e < 3 * 34 * 4; e += 256) {
        int cc4 = e & 3;
        int t   = e >> 2;
        int cl  = t % 34;                        // local padded col
        int di  = t / 34;
        int ro  = i + di - 1;
        int co  = half * 32 + cl - 1;
        float4 v = make_float4(0.f, 0.f, 0.f, 0.f);
        if (ro >= 0 && ro < H_ && co >= 0 && co < W_)
            v = *reinterpret_cast<const float4*>(
                    x + ((b * H_ + ro) * W_ + co) * C_ + cc4 * 4);
        float p0 = h2f(pack2(v.x, v.y));
        float p1 = h2f(pack2(v.z, v.w));
        int cc0 = cc4 * 2, cc1 = cc0 + 1;
        xaf[(di * 8 + cc0) * 36 + cl] = p0;
        xaf[(di * 8 + cc1) * 36 + cl] = p1;
        if (cl >= 1) {
            xbf[(di * 8 + cc0) * 36 + cl - 1] = p0;
            xbf[(di * 8 + cc1) * 36 + cl - 1] = p1;
        }
    }
    __syncthreads();

    const int lane = tid & 63;
    const int f    = lane & 31;
    const int ps   = lane >> 5;
    const int w    = tid >> 6;          // wave 0..3
    const int w2   = w * 2;             // window base in float4 units (= col w*8)

    float acc[4][4];                    // [it][r]
    #pragma unroll
    for (int it = 0; it < 4; ++it)
        #pragma unroll
        for (int r = 0; r < 4; ++r) acc[it][r] = 0.f;

    // per-lane x window base pointer (ps selects the shifted copy)
    const float4* xp0 = (ps ? &xb[0][0][0] : &xa[0][0][0]) + w2;

    #pragma unroll 1
    for (int cc = 0; cc < 8; ++cc) {
        // weights: 5 ds_read_b128
        float4 ws0 = wlds[cc][0][f];
        float4 ws1 = wlds[cc][1][f];
        float4 ws2 = wlds[cc][2][f];
        float4 ws3 = wlds[cc][3][f];
        float4 ws4 = wlds[cc][4][f];
        h2 wt[9], wk[9];
        wt[0] = f2h(ws0.x); wk[0] = f2h(ws0.y); wt[1] = f2h(ws0.z); wk[1] = f2h(ws0.w);
        wt[2] = f2h(ws1.x); wk[2] = f2h(ws1.y); wt[3] = f2h(ws1.z); wk[3] = f2h(ws1.w);
        wt[4] = f2h(ws2.x); wk[4] = f2h(ws2.y); wt[5] = f2h(ws2.z); wk[5] = f2h(ws2.w);
        wt[6] = f2h(ws3.x); wk[6] = f2h(ws3.y); wt[7] = f2h(ws3.z); wk[7] = f2h(ws3.w);
        wt[8] = f2h(ws4.x); wk[8] = f2h(ws4.y);

        // x window: 3 rows x 3 aligned float4 (12 h2 cols, 9 used)
        const float4* xp = xp0 + cc * 9;
        float xc[3][12];
        #pragma unroll
        for (int dr = 0; dr < 3; ++dr) {
            float4 a  = xp[dr * 72 + 0];
            float4 b4 = xp[dr * 72 + 1];
            float4 c  = xp[dr * 72 + 2];
            xc[dr][0] = a.x;  xc[dr][1] = a.y;  xc[dr][2]  = a.z;  xc[dr][3]  = a.w;
            xc[dr][4] = b4.x; xc[dr][5] = b4.y; xc[dr][6]  = b4.z; xc[dr][7]  = b4.w;
            xc[dr][8] = c.x;  xc[dr][9] = c.y;  xc[dr][10] = c.z;  xc[dr][11] = c.w;
        }

        #pragma unroll
        for (int it = 0; it < 4; ++it) {
            #pragma unroll
            for (int r = 0; r < 4; ++r) {
                h2 z[9];
                #pragma unroll
                for (int q = 0; q < 9; ++q) {
                    const int a = q / 3, bq = q % 3;
                    int di, dj;
                    switch (r) {   // x position = rot_r^{-1}(weight position q)
                        case 0:  di = a;      dj = bq;     break;
                        case 1:  di = 2 - bq; dj = a;      break;
                        case 2:  di = 2 - a;  dj = 2 - bq; break;
                        default: di = bq;     dj = 2 - a;  break;
                    }
                    z[q] = f2h(xc[di][it * 2 + dj]) * wt[q] + wk[q];   // v_pk_fma_f16
                }
                h2 m1 = __builtin_elementwise_max(__builtin_elementwise_max(z[0], z[1]), z[2]);
                h2 m2 = __builtin_elementwise_max(__builtin_elementwise_max(z[3], z[4]), z[5]);
                h2 m3 = __builtin_elementwise_max(__builtin_elementwise_max(z[6], z[7]), z[8]);
                h2 mm = __builtin_elementwise_max(__builtin_elementwise_max(m1, m2), m3);
                acc[it][r] = acc_dot2(mm, acc[it][r]);   // f32 accumulate
            }
        }
    }

    // ---- store: out[b, r, i, jg + it*2, f]; per (r,it) wave stores 256B
    const int jg = half * 32 + w * 8 + ps;
    #pragma unroll
    for (int r = 0; r < 4; ++r) {
        float* op = out + ((((b * 4 + r) * H_ + i) * W_ + jg) * F_ + f);
        #pragma unroll
        for (int it = 0; it < 4; ++it)
            op[it * 2 * F_] = acc[it][r];
    }
}

extern "C" void kernel_launch(void* const* d_in, const int* in_sizes, int n_in,
                              void* d_out, int out_size, void* d_ws, size_t ws_size,
                              hipStream_t stream) {
    const float* x    = (const float*)d_in[0];
    const float* kern = (const float*)d_in[1];
    const float* tker = (const float*)d_in[2];
    float* out = (float*)d_out;

    hipLaunchKernelGGL(mtp_main, dim3(B_ * H_ * 2), dim3(256), 0, stream,
                       x, kern, tker, out);
}